// Round 8
// baseline (444.496 us; speedup 1.0000x reference)
//
#include <hip/hip_runtime.h>

#define NN     2048
#define DIM    512
#define NH     8
#define HD     64
#define NE     32768
#define EPAD   32832
#define CHUNKS 8
#define CHSZ   (NN/CHUNKS)      /* 256 keys per chunk */
#define NJT    (CHSZ/64)        /* 4 key-tiles of 64 per chunk */
#define QBLK   16
#define LOG2E  1.4426950408889634f

typedef __attribute__((ext_vector_type(8))) short bf16x8;
typedef __attribute__((ext_vector_type(4))) float f32x4;

#define MFMA(a,b,c) __builtin_amdgcn_mfma_f32_16x16x32_bf16((a),(b),(c),0,0,0)

__device__ __forceinline__ float bf2f(unsigned int u16){
  union { unsigned int i; float f; } v; v.i = u16 << 16; return v.f;
}
__device__ __forceinline__ unsigned short f2bf(float f){
  union { float ff; unsigned int i; } v; v.ff = f;
  return (unsigned short)((v.i + 0x7fffu + ((v.i >> 16) & 1u)) >> 16);
}

// ---------------- fused prep: cvt (blocks 0..1539) + weight transpose (blocks 1540..2563) ----------------
__global__ __launch_bounds__(256) void prep_k(
    const float* __restrict__ X, const float* __restrict__ ef, const float* __restrict__ ew,
    unsigned short* __restrict__ Xb, unsigned short* __restrict__ pEF, unsigned short* __restrict__ pEW,
    const float* __restrict__ a0, const float* __restrict__ a1,
    const float* __restrict__ a2, const float* __restrict__ a3,
    unsigned short* __restrict__ Wt)
{
  __shared__ unsigned short tile[32][33];
  if (blockIdx.x < 1540){
    long g = (long)blockIdx.x*256 + threadIdx.x;   // 8-element group index
    const long GX = (long)NN*DIM/8;                // 131072 groups
    const long GE = (long)EPAD*8;                  // 262656 groups
    const float* src; unsigned short* dst; long off, lim8;
    if (g < GX){ src = X;  dst = Xb;  off = g;        lim8 = GX; }
    else if (g < GX+GE){ src = ef; dst = pEF; off = g-GX; lim8 = (long)NE*8; }
    else { off = g-GX-GE; if (off >= 512) return; src = ew; dst = pEW; lim8 = 320; }
    unsigned short o[8];
    if (off < lim8){
      #pragma unroll
      for (int i=0;i<8;i++) o[i] = f2bf(src[off*8+i]);
    } else {
      #pragma unroll
      for (int i=0;i<8;i++) o[i] = 0;
    }
    *(uint4*)(dst + off*8) = *(const uint4*)o;
  } else {
    int b2 = blockIdx.x - 1540;                    // 0..1023
    int bz = b2 >> 8, rem = b2 & 255;
    int bx = (rem & 15)*32, by = (rem >> 4)*32;
    int tx = threadIdx.x & 31, ty = threadIdx.x >> 5;
    const float* src = bz==0 ? a0 : bz==1 ? a1 : bz==2 ? a2 : a3;
    unsigned short* dst = Wt + (size_t)bz*DIM*DIM;
    #pragma unroll
    for (int i=0;i<32;i+=8) tile[ty+i][tx] = f2bf(src[(size_t)(by+ty+i)*DIM + bx+tx]);
    __syncthreads();
    #pragma unroll
    for (int i=0;i<32;i+=8) dst[(size_t)(bx+ty+i)*DIM + by+tx] = tile[tx][ty+i];
  }
}

// ---------------- generic C[M][N] = A1[M][K] * A2[N][K]^T + bias (final O-proj) ----------------
__global__ __launch_bounds__(256) void gemm_bt(
    const unsigned short* __restrict__ A1, const unsigned short* __restrict__ A2,
    const float* __restrict__ bias, unsigned short* __restrict__ C, float* __restrict__ Cf,
    int M, int N, int K, int bias_row)
{
  int lane = threadIdx.x & 63, w = threadIdx.x >> 6;
  int quad = lane >> 4, low = lane & 15;
  int m0 = blockIdx.y*64 + w*16;
  int n0 = blockIdx.x*32;
  f32x4 acc[2];
  acc[0] = (f32x4){0.f,0.f,0.f,0.f};
  acc[1] = (f32x4){0.f,0.f,0.f,0.f};
  #pragma unroll 4
  for (int k0=0; k0<K; k0+=32){
    bf16x8 a = *(const bf16x8*)(A1 + (size_t)(m0+low)*K + k0 + quad*8);
    #pragma unroll
    for (int t=0;t<2;t++){
      bf16x8 b = *(const bf16x8*)(A2 + (size_t)(n0+16*t+low)*K + k0 + quad*8);
      acc[t] = MFMA(a, b, acc[t]);
    }
  }
  #pragma unroll
  for (int t=0;t<2;t++){
    #pragma unroll
    for (int r=0;r<4;r++){
      int row = m0 + quad*4 + r;
      int col = n0 + 16*t + low;
      float v = acc[t][r];
      if (bias) v += bias[bias_row ? row : col];
      if (Cf) Cf[(size_t)row*N + col] = v;
      else    C [(size_t)row*N + col] = f2bf(v);
    }
  }
}

// ---------------- T2 gemm: T2L[l][e][h] = pEF[e]·pEW[l*8+h], per-l 16B rows ----------------
__global__ __launch_bounds__(256) void gemm_t2(
    const unsigned short* __restrict__ A1, const unsigned short* __restrict__ A2,
    unsigned short* __restrict__ T2L)
{
  int lane = threadIdx.x & 63, w = threadIdx.x >> 6;
  int quad = lane >> 4, low = lane & 15;
  int m0 = blockIdx.y*64 + w*16;
  int n0 = blockIdx.x*32;
  f32x4 acc[2];
  acc[0] = (f32x4){0.f,0.f,0.f,0.f};
  acc[1] = (f32x4){0.f,0.f,0.f,0.f};
  #pragma unroll
  for (int k0=0; k0<64; k0+=32){
    bf16x8 a = *(const bf16x8*)(A1 + (size_t)(m0+low)*64 + k0 + quad*8);
    #pragma unroll
    for (int t=0;t<2;t++){
      bf16x8 b = *(const bf16x8*)(A2 + (size_t)(n0+16*t+low)*64 + k0 + quad*8);
      acc[t] = MFMA(a, b, acc[t]);
    }
  }
  #pragma unroll
  for (int t=0;t<2;t++){
    #pragma unroll
    for (int r=0;r<4;r++){
      int row = m0 + quad*4 + r;            // edge index
      int col = n0 + 16*t + low;            // l*8+h
      T2L[((size_t)(col>>3)*EPAD + row)*8 + (col&7)] = f2bf(acc[t][r]);
    }
  }
}

// ---------------- gather: one (n,m) pair -> bias[n][m][0..7] bf16 ----------------
// R6 lesson: T2L loads must be normal cached loads (nt = L2-evict-first => HBM-bound).
__device__ __forceinline__ void gather_pair(long pix,
    const unsigned short* __restrict__ T2L, const float* sptab,
    const int* __restrict__ dist, const int* __restrict__ sp,
    const int* __restrict__ maskp, unsigned short* __restrict__ biasB)
{
  int dd = __builtin_nontemporal_load(dist + pix);
  int mk = __builtin_nontemporal_load(maskp + pix);
  int e[5];
  #pragma unroll
  for (int l=0;l<5;l++) e[l] = __builtin_nontemporal_load(sp + pix*5 + l);
  dd = dd < 0 ? 0 : (dd > 5 ? 5 : dd);
  float b[8];
  #pragma unroll
  for (int x=0;x<8;x++) b[x] = sptab[dd*8 + x];
  #pragma unroll
  for (int l=0;l<5;l++){
    int ee = e[l];
    if ((unsigned)ee > (unsigned)NE) ee = NE;
    uint4 tv = *(const uint4*)(T2L + ((size_t)l*EPAD + ee)*8);
    b[0] += bf2f(tv.x & 0xffffu); b[1] += bf2f(tv.x >> 16);
    b[2] += bf2f(tv.y & 0xffffu); b[3] += bf2f(tv.y >> 16);
    b[4] += bf2f(tv.z & 0xffffu); b[5] += bf2f(tv.z >> 16);
    b[6] += bf2f(tv.w & 0xffffu); b[7] += bf2f(tv.w >> 16);
  }
  unsigned short o[8];
  #pragma unroll
  for (int x=0;x<8;x++) o[x] = mk ? f2bf(-1e30f) : f2bf(b[x]);
  *(uint4*)(biasB + pix*8) = *(const uint4*)o;
}

// ---------------- attention tile body (QBLK=16, 3-barrier, packed-P) ----------------
__device__ __forceinline__ void attn_tile(int q0, int chunk,
    float (*sld)[QBLK][68],
    const unsigned short* __restrict__ Qb, const unsigned short* __restrict__ Kb,
    const unsigned short* __restrict__ Vt, const unsigned short* __restrict__ biasB,
    float* __restrict__ partO)
{
  unsigned int* p2 = (unsigned int*)sld;   // packed-P view: p2[pr*1088 + row*68 + col]
  int tid = threadIdx.x;
  int lane = tid & 63, h = tid >> 6;
  int quad = lane >> 4, low = lane & 15;

  bf16x8 aq[2];
  #pragma unroll
  for (int s=0;s<2;s++)
    aq[s] = *(const bf16x8*)(Qb + (size_t)(q0+low)*DIM + h*HD + s*32 + quad*8);

  f32x4 accO[4];
  #pragma unroll
  for (int t=0;t<4;t++) accO[t] = (f32x4){0.f,0.f,0.f,0.f};

  uint4 pb[2];
  #pragma unroll
  for (int it=0; it<2; ++it){
    int p = tid + it*512;
    int qq = p >> 6, mm = p & 63;
    pb[it] = *(const uint4*)(biasB + ((size_t)(q0+qq)*NN + chunk*CHSZ + mm)*8);
  }

  for (int jt=0; jt<NJT; ++jt){
    int m0 = chunk*CHSZ + jt*64;

    // phase B: S = Q K^T (regs only)
    f32x4 S[4];
    #pragma unroll
    for (int t=0;t<4;t++) S[t] = (f32x4){0.f,0.f,0.f,0.f};
    #pragma unroll
    for (int s=0;s<2;s++){
      #pragma unroll
      for (int t=0;t<4;t++){
        bf16x8 bk = *(const bf16x8*)(Kb + (size_t)(m0+16*t+low)*DIM + h*HD + s*32 + quad*8);
        S[t] = MFMA(aq[s], bk, S[t]);
      }
    }
    __syncthreads();   // prev phase-D readers done (wait hides under MFMA)

    #pragma unroll
    for (int t=0;t<4;t++){
      #pragma unroll
      for (int r=0;r<4;r++)
        sld[h][quad*4+r][low+16*t] = S[t][r]*0.125f;
    }
    __syncthreads();

    // phase C: bias add (regs) + softmax over heads + packed-P write (own slot)
    #pragma unroll
    for (int it=0; it<2; ++it){
      int p = tid + it*512;
      int qq = p >> 6, mm = p & 63;
      uint4 tv = pb[it];
      float s0[8];
      s0[0] = sld[0][qq][mm] + bf2f(tv.x & 0xffffu);
      s0[1] = sld[1][qq][mm] + bf2f(tv.x >> 16);
      s0[2] = sld[2][qq][mm] + bf2f(tv.y & 0xffffu);
      s0[3] = sld[3][qq][mm] + bf2f(tv.y >> 16);
      s0[4] = sld[4][qq][mm] + bf2f(tv.z & 0xffffu);
      s0[5] = sld[5][qq][mm] + bf2f(tv.z >> 16);
      s0[6] = sld[6][qq][mm] + bf2f(tv.w & 0xffffu);
      s0[7] = sld[7][qq][mm] + bf2f(tv.w >> 16);
      float mx = s0[0];
      #pragma unroll
      for (int x=1;x<8;x++) mx = fmaxf(mx, s0[x]);
      float sum = 0.f;
      #pragma unroll
      for (int x=0;x<8;x++){ s0[x] = exp2f((s0[x]-mx)*LOG2E); sum += s0[x]; }
      float inv = (mx < -1e29f) ? 0.f : 1.f/sum;
      #pragma unroll
      for (int pr=0;pr<4;pr++){
        unsigned int u = (unsigned int)f2bf(s0[2*pr]*inv)
                       | ((unsigned int)f2bf(s0[2*pr+1]*inv) << 16);
        p2[pr*1088 + qq*68 + mm] = u;
      }
    }
    if (jt+1 < NJT){
      #pragma unroll
      for (int it=0; it<2; ++it){
        int p = tid + it*512;
        int qq = p >> 6, mm = p & 63;
        pb[it] = *(const uint4*)(biasB + ((size_t)(q0+qq)*NN + m0 + 64 + mm)*8);
      }
    }
    __syncthreads();

    // phase D: O += P V
    bf16x8 ap[2];
    #pragma unroll
    for (int s=0;s<2;s++){
      const uint4* pp = (const uint4*)(p2 + (h>>1)*1088 + (size_t)low*68 + s*32 + quad*8);
      uint4 w0 = pp[0], w1 = pp[1];
      bf16x8 a;
      if (h & 1){
        a[0]=(short)(w0.x>>16); a[1]=(short)(w0.y>>16); a[2]=(short)(w0.z>>16); a[3]=(short)(w0.w>>16);
        a[4]=(short)(w1.x>>16); a[5]=(short)(w1.y>>16); a[6]=(short)(w1.z>>16); a[7]=(short)(w1.w>>16);
      } else {
        a[0]=(short)(w0.x&0xffffu); a[1]=(short)(w0.y&0xffffu); a[2]=(short)(w0.z&0xffffu); a[3]=(short)(w0.w&0xffffu);
        a[4]=(short)(w1.x&0xffffu); a[5]=(short)(w1.y&0xffffu); a[6]=(short)(w1.z&0xffffu); a[7]=(short)(w1.w&0xffffu);
      }
      ap[s] = a;
    }
    #pragma unroll
    for (int s=0;s<2;s++){
      #pragma unroll
      for (int t=0;t<4;t++){
        bf16x8 bv = *(const bf16x8*)(Vt + (size_t)(h*HD + 16*t + low)*NN + m0 + s*32 + quad*8);
        accO[t] = MFMA(ap[s], bv, accO[t]);
      }
    }
  }

  #pragma unroll
  for (int t=0;t<4;t++){
    #pragma unroll
    for (int r=0;r<4;r++){
      int q = quad*4 + r;
      partO[(((size_t)chunk*NN + q0 + q)*NH + h)*HD + 16*t + low] = accO[t][r];
    }
  }
}

// ---------------- stage 1: fused QKV (blocks 0..255) + gather m<1280 (blocks 256..5375) ----------------
__global__ __launch_bounds__(512, 8) void qkvgather_k(
    const unsigned short* __restrict__ T2L, const float* __restrict__ spb,
    const int* __restrict__ dist, const int* __restrict__ sp, const int* __restrict__ maskp,
    unsigned short* __restrict__ biasB,
    const unsigned short* __restrict__ Xb, const unsigned short* __restrict__ Wt,
    const float* __restrict__ bQ, const float* __restrict__ bK, const float* __restrict__ bV,
    unsigned short* __restrict__ Qb, unsigned short* __restrict__ Kb, unsigned short* __restrict__ Vtb)
{
  __shared__ float sptab[48];
  if (blockIdx.x < 256){
    // 8-wave QKV: 64x64 output tile, wave w -> rows (w&3)*16, cols (w>>2)*32
    int bid = blockIdx.x;
    int lane = threadIdx.x & 63, w = threadIdx.x >> 6;
    int quad = lane >> 4, low = lane & 15;
    int m0 = (bid >> 3)*64 + (w & 3)*16;
    int n0 = (bid & 7)*64 + (w >> 2)*32;
    f32x4 acc[3][2];
    #pragma unroll
    for (int z=0;z<3;z++){ acc[z][0]=(f32x4){0.f,0.f,0.f,0.f}; acc[z][1]=(f32x4){0.f,0.f,0.f,0.f}; }
    #pragma unroll 2
    for (int k0=0; k0<DIM; k0+=32){
      bf16x8 a = *(const bf16x8*)(Xb + (size_t)(m0+low)*DIM + k0 + quad*8);
      #pragma unroll
      for (int z=0;z<3;z++){
        #pragma unroll
        for (int t=0;t<2;t++){
          bf16x8 b = *(const bf16x8*)(Wt + (size_t)z*DIM*DIM + (size_t)(n0+16*t+low)*DIM + k0 + quad*8);
          acc[z][t] = MFMA(a, b, acc[z][t]);
        }
      }
    }
    #pragma unroll
    for (int t=0;t<2;t++){
      #pragma unroll
      for (int r=0;r<4;r++){
        int row = m0 + quad*4 + r;
        int col = n0 + 16*t + low;
        Qb[(size_t)row*DIM + col] = f2bf(acc[0][t][r] + bQ[col]);
        Kb[(size_t)row*DIM + col] = f2bf(acc[1][t][r] + bK[col]);
        Vtb[(size_t)col*NN + row] = f2bf(acc[2][t][r] + bV[col]);
      }
    }
  } else {
    if (threadIdx.x < 48) sptab[threadIdx.x] = spb[threadIdx.x];
    __syncthreads();
    unsigned int idx = (blockIdx.x - 256)*512u + threadIdx.x;   // 0 .. 2048*1280-1
    unsigned int n = idx / 1280u;
    unsigned int m = idx - n*1280u;
    gather_pair((long)n*NN + m, T2L, sptab, dist, sp, maskp, biasB);
  }
}

// ---------------- stage 2: attn chunks 0..3 (parity-interleaved) + gather m>=1280 ----------------
__global__ __launch_bounds__(512, 8) void attngather_k(
    const unsigned short* __restrict__ Qb, const unsigned short* __restrict__ Kb,
    const unsigned short* __restrict__ Vt, const unsigned short* __restrict__ biasB,
    float* __restrict__ partO,
    const unsigned short* __restrict__ T2L, const float* __restrict__ spb,
    const int* __restrict__ dist, const int* __restrict__ sp, const int* __restrict__ maskp,
    unsigned short* __restrict__ biasW)
{
  __shared__ __attribute__((aligned(16))) float sld[NH][QBLK][68];   // 34.8 KB
  __shared__ float sptab[48];
  if (blockIdx.x < 1024 && !(blockIdx.x & 1)){
    int aid = blockIdx.x >> 1;                  // 0..511
    attn_tile((aid & 127)*16, aid >> 7, sld, Qb, Kb, Vt, biasB, partO);
  } else {
    int gid = (blockIdx.x < 1024) ? (int)(blockIdx.x >> 1) : (int)(blockIdx.x - 512);  // 0..3071
    if (threadIdx.x < 48) sptab[threadIdx.x] = spb[threadIdx.x];
    __syncthreads();
    unsigned int idx = (unsigned int)gid*512u + threadIdx.x;    // 0 .. 2048*768-1
    unsigned int n = idx / 768u;
    unsigned int m = 1280u + (idx - n*768u);
    gather_pair((long)n*NN + m, T2L, sptab, dist, sp, maskp, biasW);
  }
}

// ---------------- stage 3: attn chunks 4..7 ----------------
__global__ __launch_bounds__(512, 4) void attn2_k(
    const unsigned short* __restrict__ Qb, const unsigned short* __restrict__ Kb,
    const unsigned short* __restrict__ Vt, const unsigned short* __restrict__ biasB,
    float* __restrict__ partO)
{
  __shared__ __attribute__((aligned(16))) float sld[NH][QBLK][68];
  attn_tile(blockIdx.x*16, 4 + blockIdx.y, sld, Qb, Kb, Vt, biasB, partO);
}

// ---------------- sum the CHUNKS partial O's, emit bf16 ----------------
__global__ __launch_bounds__(512) void merge_k(const float* __restrict__ partO,
                                               unsigned short* __restrict__ Obf)
{
  size_t idx = (size_t)blockIdx.x*512 + threadIdx.x;   // q*512 + h*64 + d
  float s = 0.f;
  #pragma unroll
  for (int c=0;c<CHUNKS;c++) s += partO[(size_t)c*NN*DIM + idx];
  Obf[idx] = f2bf(s);
}

extern "C" void kernel_launch(void* const* d_in, const int* in_sizes, int n_in,
                              void* d_out, int out_size, void* d_ws, size_t ws_size,
                              hipStream_t stream)
{
  const float* X    = (const float*)d_in[0];
  const int*  dist  = (const int*)d_in[3];
  const int*  sp    = (const int*)d_in[4];
  const float* ef   = (const float*)d_in[5];
  const int*  maskp = (const int*)d_in[6];
  const float* WQ   = (const float*)d_in[7];
  const float* bQ   = (const float*)d_in[8];
  const float* WK   = (const float*)d_in[9];
  const float* bK   = (const float*)d_in[10];
  const float* WV   = (const float*)d_in[11];
  const float* bV   = (const float*)d_in[12];
  const float* WO   = (const float*)d_in[13];
  const float* bO   = (const float*)d_in[14];
  const float* spb  = (const float*)d_in[15];
  const float* ew   = (const float*)d_in[16];

  char* ws = (char*)d_ws;
  unsigned short* Wt   = (unsigned short*)(ws + 0);            // 4 x 512x512 bf16 (Q,K,V,O transposed)
  unsigned short* Xb   = (unsigned short*)(ws + 2097152);      // 2048x512 bf16 node_feat
  unsigned short* Qb   = (unsigned short*)(ws + 4194304);      // 2048x512 bf16
  unsigned short* Kb   = (unsigned short*)(ws + 6291456);      // 2048x512 bf16
  unsigned short* Vtb  = (unsigned short*)(ws + 8388608);      // 512x2048 bf16 (transposed V)
  unsigned short* pEF  = (unsigned short*)(ws + 10485760);     // EPAD x 64 bf16
  unsigned short* pEW  = (unsigned short*)(ws + 14688256);     // 64 x 64 bf16
  unsigned short* T2L  = (unsigned short*)(ws + 14696448);     // [8][EPAD][8] bf16 per-l rows (4.2MB)
  unsigned short* Obf  = (unsigned short*)(ws + 18898944);     // 2048x512 bf16
  unsigned short* biasB= (unsigned short*)(ws + 20996096);     // NN x NN x 8 bf16 (67 MB)
  float*          pO   = (float*)(ws + 88104960);              // CHUNKS x 2048x512 f32 (33.5 MB; ws ~122 MB)

  prep_k<<<dim3(2564), dim3(256), 0, stream>>>(X, ef, ew, Xb, pEF, pEW, WQ, WK, WV, WO, Wt);
  gemm_t2<<<dim3(2,513), dim3(256), 0, stream>>>(pEF, pEW, T2L);
  // stage 1: qkv + gather for bias columns m<1280 (covers attn chunks 0..4)
  qkvgather_k<<<dim3(256 + 5120), dim3(512), 0, stream>>>(
      T2L, spb, dist, sp, maskp, biasB, Xb, Wt, bQ, bK, bV, Qb, Kb, Vtb);
  // stage 2: attn chunks 0..3 (bias ready) overlapped with gather m>=1280
  attngather_k<<<dim3(1024 + 2560), dim3(512), 0, stream>>>(
      Qb, Kb, Vtb, biasB, pO, T2L, spb, dist, sp, maskp, biasB);
  // stage 3: attn chunks 4..7
  attn2_k<<<dim3(128, 4), dim3(512), 0, stream>>>(Qb, Kb, Vtb, biasB, pO);
  merge_k<<<dim3(2048), dim3(512), 0, stream>>>(pO, Obf);
  gemm_bt<<<dim3(16,32), dim3(256), 0, stream>>>(Obf, Wt + 786432, bO, (unsigned short*)nullptr, (float*)d_out, NN, DIM, DIM, 0);
}

// Round 9
// 393.149 us; speedup vs baseline: 1.1306x; 1.1306x over previous
//
#include <hip/hip_runtime.h>

#define NN     2048
#define DIM    512
#define NH     8
#define HD     64
#define NE     32768
#define EPAD   32832
#define CHUNKS 8
#define CHSZ   (NN/CHUNKS)      /* 256 keys per chunk */
#define NJT    (CHSZ/64)        /* 4 key-tiles of 64 per chunk */
#define QBLK   16
#define LOG2E  1.4426950408889634f

typedef __attribute__((ext_vector_type(8))) short bf16x8;
typedef __attribute__((ext_vector_type(4))) float f32x4;
typedef __attribute__((ext_vector_type(4))) unsigned int u32x4;

#define MFMA(a,b,c) __builtin_amdgcn_mfma_f32_16x16x32_bf16((a),(b),(c),0,0,0)

__device__ __forceinline__ float bf2f(unsigned int u16){
  union { unsigned int i; float f; } v; v.i = u16 << 16; return v.f;
}
__device__ __forceinline__ unsigned short f2bf(float f){
  union { float ff; unsigned int i; } v; v.ff = f;
  return (unsigned short)((v.i + 0x7fffu + ((v.i >> 16) & 1u)) >> 16);
}

// ---------------- fused prep: cvt (blocks 0..1539) + weight transpose (blocks 1540..2563) ----------------
__global__ __launch_bounds__(256) void prep_k(
    const float* __restrict__ X, const float* __restrict__ ef, const float* __restrict__ ew,
    unsigned short* __restrict__ Xb, unsigned short* __restrict__ pEF, unsigned short* __restrict__ pEW,
    const float* __restrict__ a0, const float* __restrict__ a1,
    const float* __restrict__ a2, const float* __restrict__ a3,
    unsigned short* __restrict__ Wt)
{
  __shared__ unsigned short tile[32][33];
  if (blockIdx.x < 1540){
    long g = (long)blockIdx.x*256 + threadIdx.x;   // 8-element group index
    const long GX = (long)NN*DIM/8;                // 131072 groups
    const long GE = (long)EPAD*8;                  // 262656 groups
    const float* src; unsigned short* dst; long off, lim8;
    if (g < GX){ src = X;  dst = Xb;  off = g;        lim8 = GX; }
    else if (g < GX+GE){ src = ef; dst = pEF; off = g-GX; lim8 = (long)NE*8; }
    else { off = g-GX-GE; if (off >= 512) return; src = ew; dst = pEW; lim8 = 320; }
    unsigned short o[8];
    if (off < lim8){
      #pragma unroll
      for (int i=0;i<8;i++) o[i] = f2bf(src[off*8+i]);
    } else {
      #pragma unroll
      for (int i=0;i<8;i++) o[i] = 0;
    }
    *(uint4*)(dst + off*8) = *(const uint4*)o;
  } else {
    int b2 = blockIdx.x - 1540;                    // 0..1023
    int bz = b2 >> 8, rem = b2 & 255;
    int bx = (rem & 15)*32, by = (rem >> 4)*32;
    int tx = threadIdx.x & 31, ty = threadIdx.x >> 5;
    const float* src = bz==0 ? a0 : bz==1 ? a1 : bz==2 ? a2 : a3;
    unsigned short* dst = Wt + (size_t)bz*DIM*DIM;
    #pragma unroll
    for (int i=0;i<32;i+=8) tile[ty+i][tx] = f2bf(src[(size_t)(by+ty+i)*DIM + bx+tx]);
    __syncthreads();
    #pragma unroll
    for (int i=0;i<32;i+=8) dst[(size_t)(bx+ty+i)*DIM + by+tx] = tile[tx][ty+i];
  }
}

// ---------------- generic C[M][N] = A1[M][K] * A2[N][K]^T + bias (final O-proj) ----------------
__global__ __launch_bounds__(256) void gemm_bt(
    const unsigned short* __restrict__ A1, const unsigned short* __restrict__ A2,
    const float* __restrict__ bias, unsigned short* __restrict__ C, float* __restrict__ Cf,
    int M, int N, int K, int bias_row)
{
  int lane = threadIdx.x & 63, w = threadIdx.x >> 6;
  int quad = lane >> 4, low = lane & 15;
  int m0 = blockIdx.y*64 + w*16;
  int n0 = blockIdx.x*32;
  f32x4 acc[2];
  acc[0] = (f32x4){0.f,0.f,0.f,0.f};
  acc[1] = (f32x4){0.f,0.f,0.f,0.f};
  #pragma unroll 4
  for (int k0=0; k0<K; k0+=32){
    bf16x8 a = *(const bf16x8*)(A1 + (size_t)(m0+low)*K + k0 + quad*8);
    #pragma unroll
    for (int t=0;t<2;t++){
      bf16x8 b = *(const bf16x8*)(A2 + (size_t)(n0+16*t+low)*K + k0 + quad*8);
      acc[t] = MFMA(a, b, acc[t]);
    }
  }
  #pragma unroll
  for (int t=0;t<2;t++){
    #pragma unroll
    for (int r=0;r<4;r++){
      int row = m0 + quad*4 + r;
      int col = n0 + 16*t + low;
      float v = acc[t][r];
      if (bias) v += bias[bias_row ? row : col];
      if (Cf) Cf[(size_t)row*N + col] = v;
      else    C [(size_t)row*N + col] = f2bf(v);
    }
  }
}

// ---------------- T2 gemm: T2L[l][e][h] = pEF[e]·pEW[l*8+h], per-l 16B rows ----------------
// Layout [8][EPAD][8] bf16: each l's gather window is 525KB -> hot set (l<5) 2.6MB, L2-resident.
__global__ __launch_bounds__(256) void gemm_t2(
    const unsigned short* __restrict__ A1, const unsigned short* __restrict__ A2,
    unsigned short* __restrict__ T2L)
{
  int lane = threadIdx.x & 63, w = threadIdx.x >> 6;
  int quad = lane >> 4, low = lane & 15;
  int m0 = blockIdx.y*64 + w*16;
  int n0 = blockIdx.x*32;
  f32x4 acc[2];
  acc[0] = (f32x4){0.f,0.f,0.f,0.f};
  acc[1] = (f32x4){0.f,0.f,0.f,0.f};
  #pragma unroll
  for (int k0=0; k0<64; k0+=32){
    bf16x8 a = *(const bf16x8*)(A1 + (size_t)(m0+low)*64 + k0 + quad*8);
    #pragma unroll
    for (int t=0;t<2;t++){
      bf16x8 b = *(const bf16x8*)(A2 + (size_t)(n0+16*t+low)*64 + k0 + quad*8);
      acc[t] = MFMA(a, b, acc[t]);
    }
  }
  #pragma unroll
  for (int t=0;t<2;t++){
    #pragma unroll
    for (int r=0;r<4;r++){
      int row = m0 + quad*4 + r;            // edge index
      int col = n0 + 16*t + low;            // l*8+h
      T2L[((size_t)(col>>3)*EPAD + row)*8 + (col&7)] = f2bf(acc[t][r]);
    }
  }
}

// ---------------- co-scheduled bias-gather + fused QKV GEMM ----------------
// blocks 0..511: QKV (MFMA-bound, launched first so they start immediately);
// blocks 512..16895: bias gather (L2-request-bound). Disjoint pipes -> overlap.
// RULES (R6/R8 lessons): T2L gather loads must be NORMAL cached loads, and no
// streaming kernel (attn) may co-run with the gather — streams evict T2L from L2.
__global__ __launch_bounds__(256) void biasqkv_k(
    const unsigned short* __restrict__ T2L, const float* __restrict__ spb,
    const int* __restrict__ dist, const int* __restrict__ sp, const int* __restrict__ maskp,
    unsigned short* __restrict__ biasB,
    const unsigned short* __restrict__ Xb, const unsigned short* __restrict__ Wt,
    const float* __restrict__ bQ, const float* __restrict__ bK, const float* __restrict__ bV,
    unsigned short* __restrict__ Qb, unsigned short* __restrict__ Kb, unsigned short* __restrict__ Vtb)
{
  __shared__ float sptab[48];
  if (blockIdx.x >= 512){
    // ---------- bias gather ----------
    if (threadIdx.x < 48) sptab[threadIdx.x] = spb[threadIdx.x];
    __syncthreads();
    long pix = (long)(blockIdx.x - 512)*256 + threadIdx.x;   // n*NN + m, covers NN*NN
    int dd = __builtin_nontemporal_load(dist + pix);
    int mk = __builtin_nontemporal_load(maskp + pix);
    int e[5];
    #pragma unroll
    for (int l=0;l<5;l++) e[l] = __builtin_nontemporal_load(sp + pix*5 + l);
    dd = dd < 0 ? 0 : (dd > 5 ? 5 : dd);
    float b[8];
    #pragma unroll
    for (int x=0;x<8;x++) b[x] = sptab[dd*8 + x];
    #pragma unroll
    for (int l=0;l<5;l++){
      int ee = e[l];
      if ((unsigned)ee > (unsigned)NE) ee = NE;
      uint4 tv = *(const uint4*)(T2L + ((size_t)l*EPAD + ee)*8);   // cached: L2-resident window
      b[0] += bf2f(tv.x & 0xffffu); b[1] += bf2f(tv.x >> 16);
      b[2] += bf2f(tv.y & 0xffffu); b[3] += bf2f(tv.y >> 16);
      b[4] += bf2f(tv.z & 0xffffu); b[5] += bf2f(tv.z >> 16);
      b[6] += bf2f(tv.w & 0xffffu); b[7] += bf2f(tv.w >> 16);
    }
    unsigned short o[8];
    #pragma unroll
    for (int x=0;x<8;x++) o[x] = mk ? f2bf(-1e30f) : f2bf(b[x]);
    *(uint4*)(biasB + pix*8) = *(const uint4*)o;
  } else {
    // ---------- fused Q/K/V GEMM: A-fragment loaded once feeds 3 weights ----------
    int bid = blockIdx.x;                  // 0..511 -> (bx 0..15, by 0..31)
    int lane = threadIdx.x & 63, w = threadIdx.x >> 6;
    int quad = lane >> 4, low = lane & 15;
    int m0 = (bid >> 4)*64 + w*16;         // node row
    int n0 = (bid & 15)*32;                // output col
    f32x4 acc[3][2];
    #pragma unroll
    for (int z=0;z<3;z++){ acc[z][0]=(f32x4){0.f,0.f,0.f,0.f}; acc[z][1]=(f32x4){0.f,0.f,0.f,0.f}; }
    #pragma unroll 2
    for (int k0=0; k0<DIM; k0+=32){
      bf16x8 a = *(const bf16x8*)(Xb + (size_t)(m0+low)*DIM + k0 + quad*8);
      #pragma unroll
      for (int z=0;z<3;z++){
        #pragma unroll
        for (int t=0;t<2;t++){
          bf16x8 b = *(const bf16x8*)(Wt + (size_t)z*DIM*DIM + (size_t)(n0+16*t+low)*DIM + k0 + quad*8);
          acc[z][t] = MFMA(a, b, acc[z][t]);
        }
      }
    }
    #pragma unroll
    for (int t=0;t<2;t++){
      #pragma unroll
      for (int r=0;r<4;r++){
        int row = m0 + quad*4 + r;
        int col = n0 + 16*t + low;
        Qb[(size_t)row*DIM + col] = f2bf(acc[0][t][r] + bQ[col]);
        Kb[(size_t)row*DIM + col] = f2bf(acc[1][t][r] + bK[col]);
        Vtb[(size_t)col*NN + row] = f2bf(acc[2][t][r] + bV[col]);
      }
    }
  }
}

// ---------------- fused attention (QBLK=16, 4 blocks/CU, 3-barrier, packed-P) ----------------
// block = 512 threads = 8 waves, wave h owns head h; grid (128 q-tiles, 8 chunks).
// Softmax over HEADS per (q,m) pair (reference uses axis=-1 on (n,m,h)!).
// 34.8KB LDS + launch_bounds(512,8) -> 4 blocks/CU (32 waves): barrier stalls of one
// block interleave with the other 3. biasB read via nt (read-once stream, keeps K/V in L2).
__global__ __launch_bounds__(512, 8) void attn_k(
    const unsigned short* __restrict__ Qb, const unsigned short* __restrict__ Kb,
    const unsigned short* __restrict__ Vt, const unsigned short* __restrict__ biasB,
    float* __restrict__ partO)
{
  __shared__ __attribute__((aligned(16))) float sld[NH][QBLK][68];   // 34.8 KB
  unsigned int* p2 = (unsigned int*)sld;   // packed-P view: p2[pr*1088 + row*68 + col]
  int tid = threadIdx.x;
  int lane = tid & 63, h = tid >> 6;
  int quad = lane >> 4, low = lane & 15;
  int q0 = blockIdx.x * QBLK;
  int chunk = blockIdx.y;

  bf16x8 aq[2];
  #pragma unroll
  for (int s=0;s<2;s++)
    aq[s] = *(const bf16x8*)(Qb + (size_t)(q0+low)*DIM + h*HD + s*32 + quad*8);

  f32x4 accO[4];
  #pragma unroll
  for (int t=0;t<4;t++) accO[t] = (f32x4){0.f,0.f,0.f,0.f};

  // prefetch first key-tile's bias (coalesced; nt = evict-first, read-once stream)
  u32x4 pb[2];
  #pragma unroll
  for (int it=0; it<2; ++it){
    int p = tid + it*512;
    int qq = p >> 6, mm = p & 63;
    pb[it] = __builtin_nontemporal_load(
        (const u32x4*)(biasB + ((size_t)(q0+qq)*NN + chunk*CHSZ + mm)*8));
  }

  for (int jt=0; jt<NJT; ++jt){
    int m0 = chunk*CHSZ + jt*64;

    // phase B: S = Q K^T (regs only)
    f32x4 S[4];
    #pragma unroll
    for (int t=0;t<4;t++) S[t] = (f32x4){0.f,0.f,0.f,0.f};
    #pragma unroll
    for (int s=0;s<2;s++){
      #pragma unroll
      for (int t=0;t<4;t++){
        bf16x8 bk = *(const bf16x8*)(Kb + (size_t)(m0+16*t+low)*DIM + h*HD + s*32 + quad*8);
        S[t] = MFMA(aq[s], bk, S[t]);
      }
    }
    __syncthreads();   // prev phase-D readers done (wait hides under MFMA)

    #pragma unroll
    for (int t=0;t<4;t++){
      #pragma unroll
      for (int r=0;r<4;r++)
        sld[h][quad*4+r][low+16*t] = S[t][r]*0.125f;
    }
    __syncthreads();

    // phase C: bias add (regs) + softmax over heads + packed-P write (own slot)
    #pragma unroll
    for (int it=0; it<2; ++it){
      int p = tid + it*512;
      int qq = p >> 6, mm = p & 63;
      u32x4 tv = pb[it];
      float s0[8];
      s0[0] = sld[0][qq][mm] + bf2f(tv[0] & 0xffffu);
      s0[1] = sld[1][qq][mm] + bf2f(tv[0] >> 16);
      s0[2] = sld[2][qq][mm] + bf2f(tv[1] & 0xffffu);
      s0[3] = sld[3][qq][mm] + bf2f(tv[1] >> 16);
      s0[4] = sld[4][qq][mm] + bf2f(tv[2] & 0xffffu);
      s0[5] = sld[5][qq][mm] + bf2f(tv[2] >> 16);
      s0[6] = sld[6][qq][mm] + bf2f(tv[3] & 0xffffu);
      s0[7] = sld[7][qq][mm] + bf2f(tv[3] >> 16);
      float mx = s0[0];
      #pragma unroll
      for (int x=1;x<8;x++) mx = fmaxf(mx, s0[x]);
      float sum = 0.f;
      #pragma unroll
      for (int x=0;x<8;x++){ s0[x] = exp2f((s0[x]-mx)*LOG2E); sum += s0[x]; }
      float inv = (mx < -1e29f) ? 0.f : 1.f/sum;   // fully-masked pair -> zero weights
      #pragma unroll
      for (int pr=0;pr<4;pr++){
        unsigned int u = (unsigned int)f2bf(s0[2*pr]*inv)
                       | ((unsigned int)f2bf(s0[2*pr+1]*inv) << 16);
        p2[pr*1088 + qq*68 + mm] = u;
      }
    }
    if (jt+1 < NJT){
      #pragma unroll
      for (int it=0; it<2; ++it){
        int p = tid + it*512;
        int qq = p >> 6, mm = p & 63;
        pb[it] = __builtin_nontemporal_load(
            (const u32x4*)(biasB + ((size_t)(q0+qq)*NN + m0 + 64 + mm)*8));
      }
    }
    __syncthreads();

    // phase D: O += P V
    bf16x8 ap[2];
    #pragma unroll
    for (int s=0;s<2;s++){
      const uint4* pp = (const uint4*)(p2 + (h>>1)*1088 + (size_t)low*68 + s*32 + quad*8);
      uint4 w0 = pp[0], w1 = pp[1];
      bf16x8 a;
      if (h & 1){
        a[0]=(short)(w0.x>>16); a[1]=(short)(w0.y>>16); a[2]=(short)(w0.z>>16); a[3]=(short)(w0.w>>16);
        a[4]=(short)(w1.x>>16); a[5]=(short)(w1.y>>16); a[6]=(short)(w1.z>>16); a[7]=(short)(w1.w>>16);
      } else {
        a[0]=(short)(w0.x&0xffffu); a[1]=(short)(w0.y&0xffffu); a[2]=(short)(w0.z&0xffffu); a[3]=(short)(w0.w&0xffffu);
        a[4]=(short)(w1.x&0xffffu); a[5]=(short)(w1.y&0xffffu); a[6]=(short)(w1.z&0xffffu); a[7]=(short)(w1.w&0xffffu);
      }
      ap[s] = a;
    }
    #pragma unroll
    for (int s=0;s<2;s++){
      #pragma unroll
      for (int t=0;t<4;t++){
        bf16x8 bv = *(const bf16x8*)(Vt + (size_t)(h*HD + 16*t + low)*NN + m0 + s*32 + quad*8);
        accO[t] = MFMA(ap[s], bv, accO[t]);
      }
    }
  }

  // epilogue: per-chunk partial O (plain sum over m; no softmax state)
  #pragma unroll
  for (int t=0;t<4;t++){
    #pragma unroll
    for (int r=0;r<4;r++){
      int q = quad*4 + r;
      partO[(((size_t)chunk*NN + q0 + q)*NH + h)*HD + 16*t + low] = accO[t][r];
    }
  }
}

// ---------------- sum the CHUNKS partial O's, emit bf16 ----------------
__global__ __launch_bounds__(512) void merge_k(const float* __restrict__ partO,
                                               unsigned short* __restrict__ Obf)
{
  size_t idx = (size_t)blockIdx.x*512 + threadIdx.x;   // q*512 + h*64 + d
  float s = 0.f;
  #pragma unroll
  for (int c=0;c<CHUNKS;c++) s += partO[(size_t)c*NN*DIM + idx];
  Obf[idx] = f2bf(s);
}

extern "C" void kernel_launch(void* const* d_in, const int* in_sizes, int n_in,
                              void* d_out, int out_size, void* d_ws, size_t ws_size,
                              hipStream_t stream)
{
  const float* X    = (const float*)d_in[0];
  const int*  dist  = (const int*)d_in[3];
  const int*  sp    = (const int*)d_in[4];
  const float* ef   = (const float*)d_in[5];
  const int*  maskp = (const int*)d_in[6];
  const float* WQ   = (const float*)d_in[7];
  const float* bQ   = (const float*)d_in[8];
  const float* WK   = (const float*)d_in[9];
  const float* bK   = (const float*)d_in[10];
  const float* WV   = (const float*)d_in[11];
  const float* bV   = (const float*)d_in[12];
  const float* WO   = (const float*)d_in[13];
  const float* bO   = (const float*)d_in[14];
  const float* spb  = (const float*)d_in[15];
  const float* ew   = (const float*)d_in[16];

  char* ws = (char*)d_ws;
  unsigned short* Wt   = (unsigned short*)(ws + 0);            // 4 x 512x512 bf16 (Q,K,V,O transposed)
  unsigned short* Xb   = (unsigned short*)(ws + 2097152);      // 2048x512 bf16 node_feat
  unsigned short* Qb   = (unsigned short*)(ws + 4194304);      // 2048x512 bf16
  unsigned short* Kb   = (unsigned short*)(ws + 6291456);      // 2048x512 bf16
  unsigned short* Vtb  = (unsigned short*)(ws + 8388608);      // 512x2048 bf16 (transposed V)
  unsigned short* pEF  = (unsigned short*)(ws + 10485760);     // EPAD x 64 bf16
  unsigned short* pEW  = (unsigned short*)(ws + 14688256);     // 64 x 64 bf16
  unsigned short* T2L  = (unsigned short*)(ws + 14696448);     // [8][EPAD][8] bf16 per-l rows (4.2MB)
  unsigned short* Obf  = (unsigned short*)(ws + 18898944);     // 2048x512 bf16
  unsigned short* biasB= (unsigned short*)(ws + 20996096);     // NN x NN x 8 bf16 (67 MB)
  float*          pO   = (float*)(ws + 88104960);              // CHUNKS x 2048x512 f32 (33.5 MB; ws ~122 MB)

  prep_k<<<dim3(2564), dim3(256), 0, stream>>>(X, ef, ew, Xb, pEF, pEW, WQ, WK, WV, WO, Wt);
  gemm_t2<<<dim3(2,513), dim3(256), 0, stream>>>(pEF, pEW, T2L);
  biasqkv_k<<<dim3(512 + NN*NN/256), dim3(256), 0, stream>>>(
      T2L, spb, dist, sp, maskp, biasB, Xb, Wt, bQ, bK, bV, Qb, Kb, Vtb);
  attn_k<<<dim3(NN/QBLK, CHUNKS), dim3(512), 0, stream>>>(Qb, Kb, Vtb, biasB, pO);
  merge_k<<<dim3(2048), dim3(512), 0, stream>>>(pO, Obf);
  gemm_bt<<<dim3(16,32), dim3(256), 0, stream>>>(Obf, Wt + 786432, bO, (unsigned short*)nullptr, (float*)d_out, NN, DIM, DIM, 0);
}

// Round 10
// 367.955 us; speedup vs baseline: 1.2080x; 1.0685x over previous
//
#include <hip/hip_runtime.h>

#define NN     2048
#define DIM    512
#define NH     8
#define HD     64
#define NE     32768
#define EPAD   32832
#define CHUNKS 8
#define CHSZ   (NN/CHUNKS)      /* 256 keys per chunk */
#define NJT    (CHSZ/64)        /* 4 key-tiles of 64 per chunk */
#define QBLK   32
#define LOG2E  1.4426950408889634f

typedef __attribute__((ext_vector_type(8))) short bf16x8;
typedef __attribute__((ext_vector_type(4))) float f32x4;

#define MFMA(a,b,c) __builtin_amdgcn_mfma_f32_16x16x32_bf16((a),(b),(c),0,0,0)

__device__ __forceinline__ float bf2f(unsigned int u16){
  union { unsigned int i; float f; } v; v.i = u16 << 16; return v.f;
}
__device__ __forceinline__ unsigned short f2bf(float f){
  union { float ff; unsigned int i; } v; v.ff = f;
  return (unsigned short)((v.i + 0x7fffu + ((v.i >> 16) & 1u)) >> 16);
}

// ---------------- prep: node_feat->bf16 (blocks 0..511) + weight transpose (blocks 512..1535) ----------------
__global__ __launch_bounds__(256) void prep_k(
    const float* __restrict__ X, unsigned short* __restrict__ Xb,
    const float* __restrict__ a0, const float* __restrict__ a1,
    const float* __restrict__ a2, const float* __restrict__ a3,
    unsigned short* __restrict__ Wt)
{
  __shared__ unsigned short tile[32][33];
  if (blockIdx.x < 512){
    long off = (long)blockIdx.x*256 + threadIdx.x;   // 8-elem group, covers NN*DIM/8 exactly
    unsigned short o[8];
    #pragma unroll
    for (int i=0;i<8;i++) o[i] = f2bf(X[off*8+i]);
    *(uint4*)(Xb + off*8) = *(const uint4*)o;
  } else {
    int b2 = blockIdx.x - 512;                       // 0..1023
    int bz = b2 >> 8, rem = b2 & 255;
    int bx = (rem & 15)*32, by = (rem >> 4)*32;
    int tx = threadIdx.x & 31, ty = threadIdx.x >> 5;
    const float* src = bz==0 ? a0 : bz==1 ? a1 : bz==2 ? a2 : a3;
    unsigned short* dst = Wt + (size_t)bz*DIM*DIM;
    #pragma unroll
    for (int i=0;i<32;i+=8) tile[ty+i][tx] = f2bf(src[(size_t)(by+ty+i)*DIM + bx+tx]);
    __syncthreads();
    #pragma unroll
    for (int i=0;i<32;i+=8) dst[(size_t)(bx+ty+i)*DIM + by+tx] = tile[tx][ty+i];
  }
}

// ---------------- generic C[M][N] = A1[M][K] * A2[N][K]^T + bias (final O-proj) ----------------
__global__ __launch_bounds__(256) void gemm_bt(
    const unsigned short* __restrict__ A1, const unsigned short* __restrict__ A2,
    const float* __restrict__ bias, unsigned short* __restrict__ C, float* __restrict__ Cf,
    int M, int N, int K, int bias_row)
{
  int lane = threadIdx.x & 63, w = threadIdx.x >> 6;
  int quad = lane >> 4, low = lane & 15;
  int m0 = blockIdx.y*64 + w*16;
  int n0 = blockIdx.x*32;
  f32x4 acc[2];
  acc[0] = (f32x4){0.f,0.f,0.f,0.f};
  acc[1] = (f32x4){0.f,0.f,0.f,0.f};
  #pragma unroll 4
  for (int k0=0; k0<K; k0+=32){
    bf16x8 a = *(const bf16x8*)(A1 + (size_t)(m0+low)*K + k0 + quad*8);
    #pragma unroll
    for (int t=0;t<2;t++){
      bf16x8 b = *(const bf16x8*)(A2 + (size_t)(n0+16*t+low)*K + k0 + quad*8);
      acc[t] = MFMA(a, b, acc[t]);
    }
  }
  #pragma unroll
  for (int t=0;t<2;t++){
    #pragma unroll
    for (int r=0;r<4;r++){
      int row = m0 + quad*4 + r;
      int col = n0 + 16*t + low;
      float v = acc[t][r];
      if (bias) v += bias[bias_row ? row : col];
      if (Cf) Cf[(size_t)row*N + col] = v;
      else    C [(size_t)row*N + col] = f2bf(v);
    }
  }
}

// ---------------- T2 gemm from RAW f32 inputs: T2L[l][e][h] = ef[e]·ew[l*8+h] ----------------
// Reads edge_feat/edge_weight f32 directly (f2bf inline = same numerics as staged path);
// rows e>=NE and weight rows >=40 are zero. Layout [8][EPAD][8] bf16 per-l 16B rows.
__global__ __launch_bounds__(256) void gemm_t2(
    const float* __restrict__ ef, const float* __restrict__ ew,
    unsigned short* __restrict__ T2L)
{
  int lane = threadIdx.x & 63, w = threadIdx.x >> 6;
  int quad = lane >> 4, low = lane & 15;
  int m0 = blockIdx.y*64 + w*16;           // edge row
  int n0 = blockIdx.x*32;                  // col l*8+h
  f32x4 acc[2];
  acc[0] = (f32x4){0.f,0.f,0.f,0.f};
  acc[1] = (f32x4){0.f,0.f,0.f,0.f};
  #pragma unroll
  for (int k0=0; k0<64; k0+=32){
    int ar = m0 + low;
    bf16x8 a;
    if (ar < NE){
      float4 x0 = *(const float4*)(ef + (size_t)ar*64 + k0 + quad*8);
      float4 x1 = *(const float4*)(ef + (size_t)ar*64 + k0 + quad*8 + 4);
      a[0]=(short)f2bf(x0.x); a[1]=(short)f2bf(x0.y); a[2]=(short)f2bf(x0.z); a[3]=(short)f2bf(x0.w);
      a[4]=(short)f2bf(x1.x); a[5]=(short)f2bf(x1.y); a[6]=(short)f2bf(x1.z); a[7]=(short)f2bf(x1.w);
    } else {
      #pragma unroll
      for (int i=0;i<8;i++) a[i] = 0;
    }
    #pragma unroll
    for (int t=0;t<2;t++){
      int br = n0 + 16*t + low;
      bf16x8 b;
      if (br < 40){
        float4 y0 = *(const float4*)(ew + (size_t)br*64 + k0 + quad*8);
        float4 y1 = *(const float4*)(ew + (size_t)br*64 + k0 + quad*8 + 4);
        b[0]=(short)f2bf(y0.x); b[1]=(short)f2bf(y0.y); b[2]=(short)f2bf(y0.z); b[3]=(short)f2bf(y0.w);
        b[4]=(short)f2bf(y1.x); b[5]=(short)f2bf(y1.y); b[6]=(short)f2bf(y1.z); b[7]=(short)f2bf(y1.w);
      } else {
        #pragma unroll
        for (int i=0;i<8;i++) b[i] = 0;
      }
      acc[t] = MFMA(a, b, acc[t]);
    }
  }
  #pragma unroll
  for (int t=0;t<2;t++){
    #pragma unroll
    for (int r=0;r<4;r++){
      int row = m0 + quad*4 + r;            // edge index
      int col = n0 + 16*t + low;            // l*8+h
      T2L[((size_t)(col>>3)*EPAD + row)*8 + (col&7)] = f2bf(acc[t][r]);
    }
  }
}

// ---------------- co-scheduled bias-gather (+ optional fused QKV GEMM) ----------------
// Dispatch 1: blocks 0..511 = QKV, rest = gather n<1024. Dispatch 2: gather n>=1024.
// Split in two so attn_k becomes the top-duration dispatch and gets profiled.
// RULES (R6/R8/R9 lessons): T2L gather loads must be NORMAL cached loads; no streaming
// kernel may co-run with the gather (evicts T2L from L2); attn body must not be
// VGPR-capped below ~100 (launch_bounds min-waves>=8 forces scratch spill).
__global__ __launch_bounds__(256) void biasqkv_k(
    const unsigned short* __restrict__ T2L, const float* __restrict__ spb,
    const int* __restrict__ dist, const int* __restrict__ sp, const int* __restrict__ maskp,
    unsigned short* __restrict__ biasB,
    const unsigned short* __restrict__ Xb, const unsigned short* __restrict__ Wt,
    const float* __restrict__ bQ, const float* __restrict__ bK, const float* __restrict__ bV,
    unsigned short* __restrict__ Qb, unsigned short* __restrict__ Kb, unsigned short* __restrict__ Vtb,
    int nqkv, long gbase)
{
  __shared__ float sptab[48];
  if ((int)blockIdx.x >= nqkv){
    // ---------- bias gather ----------
    if (threadIdx.x < 48) sptab[threadIdx.x] = spb[threadIdx.x];
    __syncthreads();
    long pix = gbase + (long)((int)blockIdx.x - nqkv)*256 + threadIdx.x;   // n*NN + m
    int dd = __builtin_nontemporal_load(dist + pix);
    int mk = __builtin_nontemporal_load(maskp + pix);
    int e[5];
    #pragma unroll
    for (int l=0;l<5;l++) e[l] = __builtin_nontemporal_load(sp + pix*5 + l);
    dd = dd < 0 ? 0 : (dd > 5 ? 5 : dd);
    float b[8];
    #pragma unroll
    for (int x=0;x<8;x++) b[x] = sptab[dd*8 + x];
    #pragma unroll
    for (int l=0;l<5;l++){
      int ee = e[l];
      if ((unsigned)ee > (unsigned)NE) ee = NE;
      uint4 tv = *(const uint4*)(T2L + ((size_t)l*EPAD + ee)*8);   // cached: L2-resident window
      b[0] += bf2f(tv.x & 0xffffu); b[1] += bf2f(tv.x >> 16);
      b[2] += bf2f(tv.y & 0xffffu); b[3] += bf2f(tv.y >> 16);
      b[4] += bf2f(tv.z & 0xffffu); b[5] += bf2f(tv.z >> 16);
      b[6] += bf2f(tv.w & 0xffffu); b[7] += bf2f(tv.w >> 16);
    }
    unsigned short o[8];
    #pragma unroll
    for (int x=0;x<8;x++) o[x] = mk ? f2bf(-1e30f) : f2bf(b[x]);
    *(uint4*)(biasB + pix*8) = *(const uint4*)o;
  } else {
    // ---------- fused Q/K/V GEMM: A-fragment loaded once feeds 3 weights ----------
    int bid = blockIdx.x;                  // 0..511 -> (bx 0..15, by 0..31)
    int lane = threadIdx.x & 63, w = threadIdx.x >> 6;
    int quad = lane >> 4, low = lane & 15;
    int m0 = (bid >> 4)*64 + w*16;         // node row
    int n0 = (bid & 15)*32;                // output col
    f32x4 acc[3][2];
    #pragma unroll
    for (int z=0;z<3;z++){ acc[z][0]=(f32x4){0.f,0.f,0.f,0.f}; acc[z][1]=(f32x4){0.f,0.f,0.f,0.f}; }
    #pragma unroll 2
    for (int k0=0; k0<DIM; k0+=32){
      bf16x8 a = *(const bf16x8*)(Xb + (size_t)(m0+low)*DIM + k0 + quad*8);
      #pragma unroll
      for (int z=0;z<3;z++){
        #pragma unroll
        for (int t=0;t<2;t++){
          bf16x8 b = *(const bf16x8*)(Wt + (size_t)z*DIM*DIM + (size_t)(n0+16*t+low)*DIM + k0 + quad*8);
          acc[z][t] = MFMA(a, b, acc[z][t]);
        }
      }
    }
    #pragma unroll
    for (int t=0;t<2;t++){
      #pragma unroll
      for (int r=0;r<4;r++){
        int row = m0 + quad*4 + r;
        int col = n0 + 16*t + low;
        Qb[(size_t)row*DIM + col] = f2bf(acc[0][t][r] + bQ[col]);
        Kb[(size_t)row*DIM + col] = f2bf(acc[1][t][r] + bK[col]);
        Vtb[(size_t)col*NN + row] = f2bf(acc[2][t][r] + bV[col]);
      }
    }
  }
}

// ---------------- fused attention (R7 config: QBLK=32, 2 blocks/CU, 3-barrier, packed-P) ----------------
// block = 512 threads = 8 waves, wave h owns head h; grid (64 q-tiles, 8 chunks).
// Softmax over HEADS per (q,m) pair (reference uses axis=-1 on (n,m,h)!).
__global__ __launch_bounds__(512, 4) void attn_k(
    const unsigned short* __restrict__ Qb, const unsigned short* __restrict__ Kb,
    const unsigned short* __restrict__ Vt, const unsigned short* __restrict__ biasB,
    float* __restrict__ partO)
{
  __shared__ __attribute__((aligned(16))) float sld[NH][QBLK][68];  // 69.6 KB -> 2 blocks/CU
  unsigned int* p2 = (unsigned int*)sld;   // packed-P view: p2[pr*2176 + row*68 + col]
  int tid = threadIdx.x;
  int lane = tid & 63, h = tid >> 6;
  int quad = lane >> 4, low = lane & 15;
  int q0 = blockIdx.x * QBLK;
  int chunk = blockIdx.y;

  bf16x8 aq[2][2];
  #pragma unroll
  for (int sq=0;sq<2;sq++)
    #pragma unroll
    for (int s=0;s<2;s++)
      aq[sq][s] = *(const bf16x8*)(Qb + (size_t)(q0+sq*16+low)*DIM + h*HD + s*32 + quad*8);

  f32x4 accO[2][4];
  #pragma unroll
  for (int sq=0;sq<2;sq++)
    #pragma unroll
    for (int t=0;t<4;t++) accO[sq][t] = (f32x4){0.f,0.f,0.f,0.f};

  // prefetch first key-tile's bias (coalesced: consecutive tid -> consecutive 16B)
  uint4 pb[4];
  #pragma unroll
  for (int it=0; it<4; ++it){
    int p = tid + it*512;
    int qq = p >> 6, mm = p & 63;
    pb[it] = *(const uint4*)(biasB + ((size_t)(q0+qq)*NN + chunk*CHSZ + mm)*8);
  }

  for (int jt=0; jt<NJT; ++jt){
    int m0 = chunk*CHSZ + jt*64;

    // phase B: S = Q K^T (regs only)
    f32x4 S[2][4];
    #pragma unroll
    for (int sq=0;sq<2;sq++)
      #pragma unroll
      for (int t=0;t<4;t++) S[sq][t] = (f32x4){0.f,0.f,0.f,0.f};
    #pragma unroll
    for (int s=0;s<2;s++){
      #pragma unroll
      for (int t=0;t<4;t++){
        bf16x8 bk = *(const bf16x8*)(Kb + (size_t)(m0+16*t+low)*DIM + h*HD + s*32 + quad*8);
        #pragma unroll
        for (int sq=0;sq<2;sq++)
          S[sq][t] = MFMA(aq[sq][s], bk, S[sq][t]);
      }
    }
    __syncthreads();   // prev phase-D readers done (wait hides under MFMA)

    #pragma unroll
    for (int sq=0;sq<2;sq++){
      #pragma unroll
      for (int t=0;t<4;t++){
        #pragma unroll
        for (int r=0;r<4;r++)
          sld[h][sq*16+quad*4+r][low+16*t] = S[sq][t][r]*0.125f;
      }
    }
    __syncthreads();

    // phase C: bias add (regs) + softmax over heads + packed-P write (own slot)
    #pragma unroll
    for (int it=0; it<4; ++it){
      int p = tid + it*512;
      int qq = p >> 6, mm = p & 63;
      uint4 tv = pb[it];
      float s0[8];
      s0[0] = sld[0][qq][mm] + bf2f(tv.x & 0xffffu);
      s0[1] = sld[1][qq][mm] + bf2f(tv.x >> 16);
      s0[2] = sld[2][qq][mm] + bf2f(tv.y & 0xffffu);
      s0[3] = sld[3][qq][mm] + bf2f(tv.y >> 16);
      s0[4] = sld[4][qq][mm] + bf2f(tv.z & 0xffffu);
      s0[5] = sld[5][qq][mm] + bf2f(tv.z >> 16);
      s0[6] = sld[6][qq][mm] + bf2f(tv.w & 0xffffu);
      s0[7] = sld[7][qq][mm] + bf2f(tv.w >> 16);
      float mx = s0[0];
      #pragma unroll
      for (int x=1;x<8;x++) mx = fmaxf(mx, s0[x]);
      float sum = 0.f;
      #pragma unroll
      for (int x=0;x<8;x++){ s0[x] = exp2f((s0[x]-mx)*LOG2E); sum += s0[x]; }
      float inv = (mx < -1e29f) ? 0.f : 1.f/sum;   // fully-masked pair -> zero weights
      #pragma unroll
      for (int pr=0;pr<4;pr++){
        unsigned int u = (unsigned int)f2bf(s0[2*pr]*inv)
                       | ((unsigned int)f2bf(s0[2*pr+1]*inv) << 16);
        p2[pr*2176 + qq*68 + mm] = u;
      }
    }
    if (jt+1 < NJT){
      #pragma unroll
      for (int it=0; it<4; ++it){
        int p = tid + it*512;
        int qq = p >> 6, mm = p & 63;
        pb[it] = *(const uint4*)(biasB + ((size_t)(q0+qq)*NN + m0 + 64 + mm)*8);
      }
    }
    __syncthreads();

    // phase D: O += P V
    bf16x8 ap[2][2];
    #pragma unroll
    for (int sq=0;sq<2;sq++){
      #pragma unroll
      for (int s=0;s<2;s++){
        const uint4* pp = (const uint4*)(p2 + (h>>1)*2176 + (size_t)(sq*16+low)*68 + s*32 + quad*8);
        uint4 w0 = pp[0], w1 = pp[1];
        bf16x8 a;
        if (h & 1){
          a[0]=(short)(w0.x>>16); a[1]=(short)(w0.y>>16); a[2]=(short)(w0.z>>16); a[3]=(short)(w0.w>>16);
          a[4]=(short)(w1.x>>16); a[5]=(short)(w1.y>>16); a[6]=(short)(w1.z>>16); a[7]=(short)(w1.w>>16);
        } else {
          a[0]=(short)(w0.x&0xffffu); a[1]=(short)(w0.y&0xffffu); a[2]=(short)(w0.z&0xffffu); a[3]=(short)(w0.w&0xffffu);
          a[4]=(short)(w1.x&0xffffu); a[5]=(short)(w1.y&0xffffu); a[6]=(short)(w1.z&0xffffu); a[7]=(short)(w1.w&0xffffu);
        }
        ap[sq][s] = a;
      }
    }
    #pragma unroll
    for (int s=0;s<2;s++){
      #pragma unroll
      for (int t=0;t<4;t++){
        bf16x8 bv = *(const bf16x8*)(Vt + (size_t)(h*HD + 16*t + low)*NN + m0 + s*32 + quad*8);
        #pragma unroll
        for (int sq=0;sq<2;sq++)
          accO[sq][t] = MFMA(ap[sq][s], bv, accO[sq][t]);
      }
    }
  }

  // epilogue: per-chunk partial O (plain sum over m; no softmax state)
  #pragma unroll
  for (int sq=0;sq<2;sq++){
    #pragma unroll
    for (int t=0;t<4;t++){
      #pragma unroll
      for (int r=0;r<4;r++){
        int q = sq*16 + quad*4 + r;
        partO[(((size_t)chunk*NN + q0 + q)*NH + h)*HD + 16*t + low] = accO[sq][t][r];
      }
    }
  }
}

// ---------------- sum the CHUNKS partial O's, emit bf16 ----------------
__global__ __launch_bounds__(512) void merge_k(const float* __restrict__ partO,
                                               unsigned short* __restrict__ Obf)
{
  size_t idx = (size_t)blockIdx.x*512 + threadIdx.x;   // q*512 + h*64 + d
  float s = 0.f;
  #pragma unroll
  for (int c=0;c<CHUNKS;c++) s += partO[(size_t)c*NN*DIM + idx];
  Obf[idx] = f2bf(s);
}

extern "C" void kernel_launch(void* const* d_in, const int* in_sizes, int n_in,
                              void* d_out, int out_size, void* d_ws, size_t ws_size,
                              hipStream_t stream)
{
  const float* X    = (const float*)d_in[0];
  const int*  dist  = (const int*)d_in[3];
  const int*  sp    = (const int*)d_in[4];
  const float* ef   = (const float*)d_in[5];
  const int*  maskp = (const int*)d_in[6];
  const float* WQ   = (const float*)d_in[7];
  const float* bQ   = (const float*)d_in[8];
  const float* WK   = (const float*)d_in[9];
  const float* bK   = (const float*)d_in[10];
  const float* WV   = (const float*)d_in[11];
  const float* bV   = (const float*)d_in[12];
  const float* WO   = (const float*)d_in[13];
  const float* bO   = (const float*)d_in[14];
  const float* spb  = (const float*)d_in[15];
  const float* ew   = (const float*)d_in[16];

  char* ws = (char*)d_ws;
  unsigned short* Wt   = (unsigned short*)(ws + 0);            // 4 x 512x512 bf16 (Q,K,V,O transposed)
  unsigned short* Xb   = (unsigned short*)(ws + 2097152);      // 2048x512 bf16 node_feat
  unsigned short* Qb   = (unsigned short*)(ws + 4194304);      // 2048x512 bf16
  unsigned short* Kb   = (unsigned short*)(ws + 6291456);      // 2048x512 bf16
  unsigned short* Vtb  = (unsigned short*)(ws + 8388608);      // 512x2048 bf16 (transposed V)
  unsigned short* T2L  = (unsigned short*)(ws + 14696448);     // [8][EPAD][8] bf16 per-l rows (4.2MB)
  unsigned short* Obf  = (unsigned short*)(ws + 18898944);     // 2048x512 bf16
  unsigned short* biasB= (unsigned short*)(ws + 20996096);     // NN x NN x 8 bf16 (67 MB)
  float*          pO   = (float*)(ws + 88104960);              // CHUNKS x 2048x512 f32 (33.5 MB; ws ~122 MB)

  prep_k<<<dim3(1536), dim3(256), 0, stream>>>(X, Xb, WQ, WK, WV, WO, Wt);
  gemm_t2<<<dim3(2,513), dim3(256), 0, stream>>>(ef, ew, T2L);
  // gather split into 2 dispatches (each < attn) so attn_k tops the profile; qkv rides in #1
  biasqkv_k<<<dim3(512 + 8192), dim3(256), 0, stream>>>(
      T2L, spb, dist, sp, maskp, biasB, Xb, Wt, bQ, bK, bV, Qb, Kb, Vtb,
      512, 0L);
  biasqkv_k<<<dim3(8192), dim3(256), 0, stream>>>(
      T2L, spb, dist, sp, maskp, biasB, Xb, Wt, bQ, bK, bV, Qb, Kb, Vtb,
      0, (long)NN*NN/2);
  attn_k<<<dim3(NN/QBLK, CHUNKS), dim3(512), 0, stream>>>(Qb, Kb, Vtb, biasB, pO);
  merge_k<<<dim3(2048), dim3(512), 0, stream>>>(pO, Obf);
  gemm_bt<<<dim3(16,32), dim3(256), 0, stream>>>(Obf, Wt + 786432, bO, (unsigned short*)nullptr, (float*)d_out, NN, DIM, DIM, 0);
}

// Round 11
// 367.036 us; speedup vs baseline: 1.2110x; 1.0025x over previous
//
#include <hip/hip_runtime.h>

#define NN     2048
#define DIM    512
#define NH     8
#define HD     64
#define NE     32768
#define EPAD   32832
#define CHUNKS 8
#define CHSZ   (NN/CHUNKS)      /* 256 keys per chunk */
#define NJT    (CHSZ/64)        /* 4 key-tiles of 64 per chunk */
#define QBLK   32
#define LOG2E  1.4426950408889634f

typedef __attribute__((ext_vector_type(8))) short bf16x8;
typedef __attribute__((ext_vector_type(4))) float f32x4;
typedef __attribute__((ext_vector_type(4))) unsigned int u32x4;

#define MFMA(a,b,c) __builtin_amdgcn_mfma_f32_16x16x32_bf16((a),(b),(c),0,0,0)

__device__ __forceinline__ float bf2f(unsigned int u16){
  union { unsigned int i; float f; } v; v.i = u16 << 16; return v.f;
}
__device__ __forceinline__ unsigned short f2bf(float f){
  union { float ff; unsigned int i; } v; v.ff = f;
  return (unsigned short)((v.i + 0x7fffu + ((v.i >> 16) & 1u)) >> 16);
}

// ---------------- fused prep + T2 gemm ----------------
// blocks 0..511    : node_feat f32 -> bf16 Xb
// blocks 512..1535 : 4x 512x512 weight transpose f32 -> bf16 Wt
// blocks 1536..2561: T2L[l][e][h] = ef[e]·ew[l*8+h] from RAW f32 inputs
//                    (rows e>=NE and weight rows >=40 are zero)
__global__ __launch_bounds__(256) void prepT2_k(
    const float* __restrict__ X, unsigned short* __restrict__ Xb,
    const float* __restrict__ a0, const float* __restrict__ a1,
    const float* __restrict__ a2, const float* __restrict__ a3,
    unsigned short* __restrict__ Wt,
    const float* __restrict__ ef, const float* __restrict__ ew,
    unsigned short* __restrict__ T2L)
{
  __shared__ unsigned short tile[32][33];
  if (blockIdx.x < 512){
    long off = (long)blockIdx.x*256 + threadIdx.x;   // 8-elem group, covers NN*DIM/8 exactly
    unsigned short o[8];
    #pragma unroll
    for (int i=0;i<8;i++) o[i] = f2bf(X[off*8+i]);
    *(uint4*)(Xb + off*8) = *(const uint4*)o;
  } else if (blockIdx.x < 1536){
    int b2 = blockIdx.x - 512;                       // 0..1023
    int bz = b2 >> 8, rem = b2 & 255;
    int bx = (rem & 15)*32, by = (rem >> 4)*32;
    int tx = threadIdx.x & 31, ty = threadIdx.x >> 5;
    const float* src = bz==0 ? a0 : bz==1 ? a1 : bz==2 ? a2 : a3;
    unsigned short* dst = Wt + (size_t)bz*DIM*DIM;
    #pragma unroll
    for (int i=0;i<32;i+=8) tile[ty+i][tx] = f2bf(src[(size_t)(by+ty+i)*DIM + bx+tx]);
    __syncthreads();
    #pragma unroll
    for (int i=0;i<32;i+=8) dst[(size_t)(bx+ty+i)*DIM + by+tx] = tile[tx][ty+i];
  } else {
    int bt = blockIdx.x - 1536;                      // 0..1025
    int bx = bt & 1, by = bt >> 1;                   // (2, 513)
    int lane = threadIdx.x & 63, w = threadIdx.x >> 6;
    int quad = lane >> 4, low = lane & 15;
    int m0 = by*64 + w*16;                           // edge row
    int n0 = bx*32;                                  // col l*8+h
    f32x4 acc[2];
    acc[0] = (f32x4){0.f,0.f,0.f,0.f};
    acc[1] = (f32x4){0.f,0.f,0.f,0.f};
    #pragma unroll
    for (int k0=0; k0<64; k0+=32){
      int ar = m0 + low;
      bf16x8 a;
      if (ar < NE){
        float4 x0 = *(const float4*)(ef + (size_t)ar*64 + k0 + quad*8);
        float4 x1 = *(const float4*)(ef + (size_t)ar*64 + k0 + quad*8 + 4);
        a[0]=(short)f2bf(x0.x); a[1]=(short)f2bf(x0.y); a[2]=(short)f2bf(x0.z); a[3]=(short)f2bf(x0.w);
        a[4]=(short)f2bf(x1.x); a[5]=(short)f2bf(x1.y); a[6]=(short)f2bf(x1.z); a[7]=(short)f2bf(x1.w);
      } else {
        #pragma unroll
        for (int i=0;i<8;i++) a[i] = 0;
      }
      #pragma unroll
      for (int t=0;t<2;t++){
        int br = n0 + 16*t + low;
        bf16x8 b;
        if (br < 40){
          float4 y0 = *(const float4*)(ew + (size_t)br*64 + k0 + quad*8);
          float4 y1 = *(const float4*)(ew + (size_t)br*64 + k0 + quad*8 + 4);
          b[0]=(short)f2bf(y0.x); b[1]=(short)f2bf(y0.y); b[2]=(short)f2bf(y0.z); b[3]=(short)f2bf(y0.w);
          b[4]=(short)f2bf(y1.x); b[5]=(short)f2bf(y1.y); b[6]=(short)f2bf(y1.z); b[7]=(short)f2bf(y1.w);
        } else {
          #pragma unroll
          for (int i=0;i<8;i++) b[i] = 0;
        }
        acc[t] = MFMA(a, b, acc[t]);
      }
    }
    #pragma unroll
    for (int t=0;t<2;t++){
      #pragma unroll
      for (int r=0;r<4;r++){
        int row = m0 + quad*4 + r;            // edge index
        int col = n0 + 16*t + low;            // l*8+h
        T2L[((size_t)(col>>3)*EPAD + row)*8 + (col&7)] = f2bf(acc[t][r]);
      }
    }
  }
}

// ---------------- generic C[M][N] = A1[M][K] * A2[N][K]^T + bias (final O-proj) ----------------
__global__ __launch_bounds__(256) void gemm_bt(
    const unsigned short* __restrict__ A1, const unsigned short* __restrict__ A2,
    const float* __restrict__ bias, unsigned short* __restrict__ C, float* __restrict__ Cf,
    int M, int N, int K, int bias_row)
{
  int lane = threadIdx.x & 63, w = threadIdx.x >> 6;
  int quad = lane >> 4, low = lane & 15;
  int m0 = blockIdx.y*64 + w*16;
  int n0 = blockIdx.x*32;
  f32x4 acc[2];
  acc[0] = (f32x4){0.f,0.f,0.f,0.f};
  acc[1] = (f32x4){0.f,0.f,0.f,0.f};
  #pragma unroll 4
  for (int k0=0; k0<K; k0+=32){
    bf16x8 a = *(const bf16x8*)(A1 + (size_t)(m0+low)*K + k0 + quad*8);
    #pragma unroll
    for (int t=0;t<2;t++){
      bf16x8 b = *(const bf16x8*)(A2 + (size_t)(n0+16*t+low)*K + k0 + quad*8);
      acc[t] = MFMA(a, b, acc[t]);
    }
  }
  #pragma unroll
  for (int t=0;t<2;t++){
    #pragma unroll
    for (int r=0;r<4;r++){
      int row = m0 + quad*4 + r;
      int col = n0 + 16*t + low;
      float v = acc[t][r];
      if (bias) v += bias[bias_row ? row : col];
      if (Cf) Cf[(size_t)row*N + col] = v;
      else    C [(size_t)row*N + col] = f2bf(v);
    }
  }
}

// ---------------- co-scheduled bias-gather + fused QKV GEMM (single dispatch) ----------------
// blocks 0..511: QKV (MFMA-bound, start first); blocks 512..16895: gather (L2-request-bound).
// RULES (R6/R8/R9/R10 lessons): T2L gather loads must be NORMAL cached loads; no streaming
// kernel may co-run with the gather (evicts T2L from L2); attn body must not be VGPR-capped
// below ~100 (spill); do NOT split the gather across dispatches (T2L re-warm + tails cost ~27us).
__global__ __launch_bounds__(256) void biasqkv_k(
    const unsigned short* __restrict__ T2L, const float* __restrict__ spb,
    const int* __restrict__ dist, const int* __restrict__ sp, const int* __restrict__ maskp,
    unsigned short* __restrict__ biasB,
    const unsigned short* __restrict__ Xb, const unsigned short* __restrict__ Wt,
    const float* __restrict__ bQ, const float* __restrict__ bK, const float* __restrict__ bV,
    unsigned short* __restrict__ Qb, unsigned short* __restrict__ Kb, unsigned short* __restrict__ Vtb)
{
  __shared__ float sptab[48];
  if (blockIdx.x >= 512){
    // ---------- bias gather ----------
    if (threadIdx.x < 48) sptab[threadIdx.x] = spb[threadIdx.x];
    __syncthreads();
    long pix = (long)(blockIdx.x - 512)*256 + threadIdx.x;   // n*NN + m, covers NN*NN
    int dd = __builtin_nontemporal_load(dist + pix);
    int mk = __builtin_nontemporal_load(maskp + pix);
    int e[5];
    #pragma unroll
    for (int l=0;l<5;l++) e[l] = __builtin_nontemporal_load(sp + pix*5 + l);
    dd = dd < 0 ? 0 : (dd > 5 ? 5 : dd);
    float b[8];
    #pragma unroll
    for (int x=0;x<8;x++) b[x] = sptab[dd*8 + x];
    #pragma unroll
    for (int l=0;l<5;l++){
      int ee = e[l];
      if ((unsigned)ee > (unsigned)NE) ee = NE;
      uint4 tv = *(const uint4*)(T2L + ((size_t)l*EPAD + ee)*8);   // cached: L2-resident window
      b[0] += bf2f(tv.x & 0xffffu); b[1] += bf2f(tv.x >> 16);
      b[2] += bf2f(tv.y & 0xffffu); b[3] += bf2f(tv.y >> 16);
      b[4] += bf2f(tv.z & 0xffffu); b[5] += bf2f(tv.z >> 16);
      b[6] += bf2f(tv.w & 0xffffu); b[7] += bf2f(tv.w >> 16);
    }
    unsigned short o[8];
    #pragma unroll
    for (int x=0;x<8;x++) o[x] = mk ? f2bf(-1e30f) : f2bf(b[x]);
    *(uint4*)(biasB + pix*8) = *(const uint4*)o;
  } else {
    // ---------- fused Q/K/V GEMM: A-fragment loaded once feeds 3 weights ----------
    int bid = blockIdx.x;                  // 0..511 -> (bx 0..15, by 0..31)
    int lane = threadIdx.x & 63, w = threadIdx.x >> 6;
    int quad = lane >> 4, low = lane & 15;
    int m0 = (bid >> 4)*64 + w*16;         // node row
    int n0 = (bid & 15)*32;                // output col
    f32x4 acc[3][2];
    #pragma unroll
    for (int z=0;z<3;z++){ acc[z][0]=(f32x4){0.f,0.f,0.f,0.f}; acc[z][1]=(f32x4){0.f,0.f,0.f,0.f}; }
    #pragma unroll 2
    for (int k0=0; k0<DIM; k0+=32){
      bf16x8 a = *(const bf16x8*)(Xb + (size_t)(m0+low)*DIM + k0 + quad*8);
      #pragma unroll
      for (int z=0;z<3;z++){
        #pragma unroll
        for (int t=0;t<2;t++){
          bf16x8 b = *(const bf16x8*)(Wt + (size_t)z*DIM*DIM + (size_t)(n0+16*t+low)*DIM + k0 + quad*8);
          acc[z][t] = MFMA(a, b, acc[z][t]);
        }
      }
    }
    #pragma unroll
    for (int t=0;t<2;t++){
      #pragma unroll
      for (int r=0;r<4;r++){
        int row = m0 + quad*4 + r;
        int col = n0 + 16*t + low;
        Qb[(size_t)row*DIM + col] = f2bf(acc[0][t][r] + bQ[col]);
        Kb[(size_t)row*DIM + col] = f2bf(acc[1][t][r] + bK[col]);
        Vtb[(size_t)col*NN + row] = f2bf(acc[2][t][r] + bV[col]);
      }
    }
  }
}

// ---------------- fused attention (QBLK=32, 2 blocks/CU, 3-barrier, packed-P) ----------------
// block = 512 threads = 8 waves, wave h owns head h; grid (64 q-tiles, 8 chunks).
// Softmax over HEADS per (q,m) pair (reference uses axis=-1 on (n,m,h)!).
// biasB read via nt (read-exactly-once stream; evict-first protects Kb/Vtb L2 residency).
__global__ __launch_bounds__(512, 4) void attn_k(
    const unsigned short* __restrict__ Qb, const unsigned short* __restrict__ Kb,
    const unsigned short* __restrict__ Vt, const unsigned short* __restrict__ biasB,
    float* __restrict__ partO)
{
  __shared__ __attribute__((aligned(16))) float sld[NH][QBLK][68];  // 69.6 KB -> 2 blocks/CU
  unsigned int* p2 = (unsigned int*)sld;   // packed-P view: p2[pr*2176 + row*68 + col]
  int tid = threadIdx.x;
  int lane = tid & 63, h = tid >> 6;
  int quad = lane >> 4, low = lane & 15;
  int q0 = blockIdx.x * QBLK;
  int chunk = blockIdx.y;

  bf16x8 aq[2][2];
  #pragma unroll
  for (int sq=0;sq<2;sq++)
    #pragma unroll
    for (int s=0;s<2;s++)
      aq[sq][s] = *(const bf16x8*)(Qb + (size_t)(q0+sq*16+low)*DIM + h*HD + s*32 + quad*8);

  f32x4 accO[2][4];
  #pragma unroll
  for (int sq=0;sq<2;sq++)
    #pragma unroll
    for (int t=0;t<4;t++) accO[sq][t] = (f32x4){0.f,0.f,0.f,0.f};

  // prefetch first key-tile's bias (coalesced; nt = evict-first, read-once stream)
  u32x4 pb[4];
  #pragma unroll
  for (int it=0; it<4; ++it){
    int p = tid + it*512;
    int qq = p >> 6, mm = p & 63;
    pb[it] = __builtin_nontemporal_load(
        (const u32x4*)(biasB + ((size_t)(q0+qq)*NN + chunk*CHSZ + mm)*8));
  }

  for (int jt=0; jt<NJT; ++jt){
    int m0 = chunk*CHSZ + jt*64;

    // phase B: S = Q K^T (regs only)
    f32x4 S[2][4];
    #pragma unroll
    for (int sq=0;sq<2;sq++)
      #pragma unroll
      for (int t=0;t<4;t++) S[sq][t] = (f32x4){0.f,0.f,0.f,0.f};
    #pragma unroll
    for (int s=0;s<2;s++){
      #pragma unroll
      for (int t=0;t<4;t++){
        bf16x8 bk = *(const bf16x8*)(Kb + (size_t)(m0+16*t+low)*DIM + h*HD + s*32 + quad*8);
        #pragma unroll
        for (int sq=0;sq<2;sq++)
          S[sq][t] = MFMA(aq[sq][s], bk, S[sq][t]);
      }
    }
    __syncthreads();   // prev phase-D readers done (wait hides under MFMA)

    #pragma unroll
    for (int sq=0;sq<2;sq++){
      #pragma unroll
      for (int t=0;t<4;t++){
        #pragma unroll
        for (int r=0;r<4;r++)
          sld[h][sq*16+quad*4+r][low+16*t] = S[sq][t][r]*0.125f;
      }
    }
    __syncthreads();

    // phase C: bias add (regs) + softmax over heads + packed-P write (own slot)
    #pragma unroll
    for (int it=0; it<4; ++it){
      int p = tid + it*512;
      int qq = p >> 6, mm = p & 63;
      u32x4 tv = pb[it];
      float s0[8];
      s0[0] = sld[0][qq][mm] + bf2f(tv[0] & 0xffffu);
      s0[1] = sld[1][qq][mm] + bf2f(tv[0] >> 16);
      s0[2] = sld[2][qq][mm] + bf2f(tv[1] & 0xffffu);
      s0[3] = sld[3][qq][mm] + bf2f(tv[1] >> 16);
      s0[4] = sld[4][qq][mm] + bf2f(tv[2] & 0xffffu);
      s0[5] = sld[5][qq][mm] + bf2f(tv[2] >> 16);
      s0[6] = sld[6][qq][mm] + bf2f(tv[3] & 0xffffu);
      s0[7] = sld[7][qq][mm] + bf2f(tv[3] >> 16);
      float mx = s0[0];
      #pragma unroll
      for (int x=1;x<8;x++) mx = fmaxf(mx, s0[x]);
      float sum = 0.f;
      #pragma unroll
      for (int x=0;x<8;x++){ s0[x] = exp2f((s0[x]-mx)*LOG2E); sum += s0[x]; }
      float inv = (mx < -1e29f) ? 0.f : 1.f/sum;   // fully-masked pair -> zero weights
      #pragma unroll
      for (int pr=0;pr<4;pr++){
        unsigned int u = (unsigned int)f2bf(s0[2*pr]*inv)
                       | ((unsigned int)f2bf(s0[2*pr+1]*inv) << 16);
        p2[pr*2176 + qq*68 + mm] = u;
      }
    }
    if (jt+1 < NJT){
      #pragma unroll
      for (int it=0; it<4; ++it){
        int p = tid + it*512;
        int qq = p >> 6, mm = p & 63;
        pb[it] = __builtin_nontemporal_load(
            (const u32x4*)(biasB + ((size_t)(q0+qq)*NN + m0 + 64 + mm)*8));
      }
    }
    __syncthreads();

    // phase D: O += P V
    bf16x8 ap[2][2];
    #pragma unroll
    for (int sq=0;sq<2;sq++){
      #pragma unroll
      for (int s=0;s<2;s++){
        const uint4* pp = (const uint4*)(p2 + (h>>1)*2176 + (size_t)(sq*16+low)*68 + s*32 + quad*8);
        uint4 w0 = pp[0], w1 = pp[1];
        bf16x8 a;
        if (h & 1){
          a[0]=(short)(w0.x>>16); a[1]=(short)(w0.y>>16); a[2]=(short)(w0.z>>16); a[3]=(short)(w0.w>>16);
          a[4]=(short)(w1.x>>16); a[5]=(short)(w1.y>>16); a[6]=(short)(w1.z>>16); a[7]=(short)(w1.w>>16);
        } else {
          a[0]=(short)(w0.x&0xffffu); a[1]=(short)(w0.y&0xffffu); a[2]=(short)(w0.z&0xffffu); a[3]=(short)(w0.w&0xffffu);
          a[4]=(short)(w1.x&0xffffu); a[5]=(short)(w1.y&0xffffu); a[6]=(short)(w1.z&0xffffu); a[7]=(short)(w1.w&0xffffu);
        }
        ap[sq][s] = a;
      }
    }
    #pragma unroll
    for (int s=0;s<2;s++){
      #pragma unroll
      for (int t=0;t<4;t++){
        bf16x8 bv = *(const bf16x8*)(Vt + (size_t)(h*HD + 16*t + low)*NN + m0 + s*32 + quad*8);
        #pragma unroll
        for (int sq=0;sq<2;sq++)
          accO[sq][t] = MFMA(ap[sq][s], bv, accO[sq][t]);
      }
    }
  }

  // epilogue: per-chunk partial O (plain sum over m; no softmax state)
  #pragma unroll
  for (int sq=0;sq<2;sq++){
    #pragma unroll
    for (int t=0;t<4;t++){
      #pragma unroll
      for (int r=0;r<4;r++){
        int q = sq*16 + quad*4 + r;
        partO[(((size_t)chunk*NN + q0 + q)*NH + h)*HD + 16*t + low] = accO[sq][t][r];
      }
    }
  }
}

// ---------------- sum the CHUNKS partial O's, emit bf16 ----------------
__global__ __launch_bounds__(512) void merge_k(const float* __restrict__ partO,
                                               unsigned short* __restrict__ Obf)
{
  size_t idx = (size_t)blockIdx.x*512 + threadIdx.x;   // q*512 + h*64 + d
  float s = 0.f;
  #pragma unroll
  for (int c=0;c<CHUNKS;c++) s += partO[(size_t)c*NN*DIM + idx];
  Obf[idx] = f2bf(s);
}

extern "C" void kernel_launch(void* const* d_in, const int* in_sizes, int n_in,
                              void* d_out, int out_size, void* d_ws, size_t ws_size,
                              hipStream_t stream)
{
  const float* X    = (const float*)d_in[0];
  const int*  dist  = (const int*)d_in[3];
  const int*  sp    = (const int*)d_in[4];
  const float* ef   = (const float*)d_in[5];
  const int*  maskp = (const int*)d_in[6];
  const float* WQ   = (const float*)d_in[7];
  const float* bQ   = (const float*)d_in[8];
  const float* WK   = (const float*)d_in[9];
  const float* bK   = (const float*)d_in[10];
  const float* WV   = (const float*)d_in[11];
  const float* bV   = (const float*)d_in[12];
  const float* WO   = (const float*)d_in[13];
  const float* bO   = (const float*)d_in[14];
  const float* spb  = (const float*)d_in[15];
  const float* ew   = (const float*)d_in[16];

  char* ws = (char*)d_ws;
  unsigned short* Wt   = (unsigned short*)(ws + 0);            // 4 x 512x512 bf16 (Q,K,V,O transposed)
  unsigned short* Xb   = (unsigned short*)(ws + 2097152);      // 2048x512 bf16 node_feat
  unsigned short* Qb   = (unsigned short*)(ws + 4194304);      // 2048x512 bf16
  unsigned short* Kb   = (unsigned short*)(ws + 6291456);      // 2048x512 bf16
  unsigned short* Vtb  = (unsigned short*)(ws + 8388608);      // 512x2048 bf16 (transposed V)
  unsigned short* T2L  = (unsigned short*)(ws + 14696448);     // [8][EPAD][8] bf16 per-l rows (4.2MB)
  unsigned short* Obf  = (unsigned short*)(ws + 18898944);     // 2048x512 bf16
  unsigned short* biasB= (unsigned short*)(ws + 20996096);     // NN x NN x 8 bf16 (67 MB)
  float*          pO   = (float*)(ws + 88104960);              // CHUNKS x 2048x512 f32 (33.5 MB; ws ~122 MB)

  prepT2_k<<<dim3(2562), dim3(256), 0, stream>>>(X, Xb, WQ, WK, WV, WO, Wt, ef, ew, T2L);
  biasqkv_k<<<dim3(512 + NN*NN/256), dim3(256), 0, stream>>>(
      T2L, spb, dist, sp, maskp, biasB, Xb, Wt, bQ, bK, bV, Qb, Kb, Vtb);
  attn_k<<<dim3(NN/QBLK, CHUNKS), dim3(512), 0, stream>>>(Qb, Kb, Vtb, biasB, pO);
  merge_k<<<dim3(2048), dim3(512), 0, stream>>>(pO, Obf);
  gemm_bt<<<dim3(16,32), dim3(256), 0, stream>>>(Obf, Wt + 786432, bO, (unsigned short*)nullptr, (float*)d_out, NN, DIM, DIM, 0);
}